// Round 4
// baseline (197.879 us; speedup 1.0000x reference)
//
#include <hip/hip_runtime.h>
#include <hip/hip_bf16.h>
#include <stdint.h>

#define N_ROWS 8192
#define DIM    1024
#define TEMP_INV 10.0f
#define NCHUNK 16
#define BM 128
#define BN 512
#define BK 32
#define NK (DIM / BK)                 // 32 K-steps
#define A_ELEMS (BM * BK)             // 4096
#define B_ELEMS (BN * BK)             // 16384
#define BUF_ELEMS (A_ELEMS + B_ELEMS) // 20480
#define B_OFF A_ELEMS

typedef __attribute__((ext_vector_type(8))) short bf16x8;
typedef __attribute__((ext_vector_type(4))) float f32x4;

__device__ __forceinline__ void gload_lds16(const void* g, void* l) {
  __builtin_amdgcn_global_load_lds(
      (const __attribute__((address_space(1))) unsigned int*)g,
      (__attribute__((address_space(3))) unsigned int*)l, 16, 0, 0);
}

__device__ __forceinline__ int sw4(int row) { return (row ^ (row >> 2)) & 3; }

__device__ __forceinline__ unsigned short f2bf(float x) {
  unsigned int u = __float_as_uint(x);
  unsigned int r = (u + 0x7FFFu + ((u >> 16) & 1u)) >> 16;
  return (unsigned short)r;
}

// -------- Kernel 1: L2-normalize rows, convert to bf16 --------
__global__ void norm_bf16_kernel(const float* __restrict__ ctx,
                                 const float* __restrict__ gls,
                                 unsigned short* __restrict__ Cn,
                                 unsigned short* __restrict__ Gn) {
  int row = blockIdx.x;
  const float* src;
  unsigned short* dst;
  if (row < N_ROWS) { src = ctx + (size_t)row * DIM; dst = Cn + (size_t)row * DIM; }
  else { src = gls + (size_t)(row - N_ROWS) * DIM; dst = Gn + (size_t)(row - N_ROWS) * DIM; }
  int t = threadIdx.x;
  float4 v = ((const float4*)src)[t];
  float ss = v.x*v.x + v.y*v.y + v.z*v.z + v.w*v.w;
  #pragma unroll
  for (int m = 1; m < 64; m <<= 1) ss += __shfl_xor(ss, m);
  __shared__ float wss[4];
  if ((t & 63) == 0) wss[t >> 6] = ss;
  __syncthreads();
  float tot = wss[0] + wss[1] + wss[2] + wss[3];
  float inv = 1.0f / fmaxf(sqrtf(tot), 1e-12f);
  unsigned short o0 = f2bf(v.x * inv);
  unsigned short o1 = f2bf(v.y * inv);
  unsigned short o2 = f2bf(v.z * inv);
  unsigned short o3 = f2bf(v.w * inv);
  unsigned long long pack = (unsigned long long)o0 | ((unsigned long long)o1 << 16) |
                            ((unsigned long long)o2 << 32) | ((unsigned long long)o3 << 48);
  *(unsigned long long*)(dst + (size_t)t * 4) = pack;
}

// -------- Kernel 2: pipelined bf16 GEMM (ring-3 LDS, counted vmcnt) + fused epilogue --------
__global__ __launch_bounds__(512, 2)
void gemm_reduce_kernel(const unsigned short* __restrict__ Cn,
                        const unsigned short* __restrict__ Gn,
                        const int* __restrict__ labels,
                        float* __restrict__ ws_sp,
                        float* __restrict__ ws_sa,
                        float* __restrict__ ws_mx) {
  __shared__ __align__(16) unsigned short lds[3 * BUF_ELEMS];  // 120 KiB ring
  __shared__ float red_sa[4][BM];
  __shared__ float red_sp[4][BM];
  __shared__ float red_mx[4][BM];

  const int tid = threadIdx.x;
  const int lane = tid & 63;
  const int wv = tid >> 6;       // 0..7
  const int wm = wv >> 2;        // 0..1  (row half)
  const int wn = wv & 3;         // 0..3  (col quarter, 128 wide)
  const int g = lane >> 4;       // 0..3
  const int fr = lane & 15;      // 0..15
  const int row0 = blockIdx.x * BM;
  const int col0 = blockIdx.y * BN;

  // ---- staging constants (LDS written linearly; swizzle pre-applied on global src) ----
  const int s_row = tid >> 2;                         // 0..127 row within an 8KB issue
  const int s_slot8 = (((tid & 3) ^ sw4(s_row)) << 3);
  const unsigned short* srcA = Cn + (size_t)(row0 + s_row) * DIM + s_slot8;
  const unsigned short* srcB = Gn + (size_t)(col0 + s_row) * DIM + s_slot8;
  const int dA = (wv << 9);                           // wave-uniform LDS elem offset

  // ---- ds_read fragment offsets (compile-time-indexed arrays) ----
  int a_off[4], b_off[8];
  #pragma unroll
  for (int mi = 0; mi < 4; ++mi) {
    int r = wm * 64 + mi * 16 + fr;
    a_off[mi] = r * BK + ((g ^ sw4(r)) << 3);
  }
  #pragma unroll
  for (int ni = 0; ni < 8; ++ni) {
    int r = wn * 128 + ni * 16 + fr;
    b_off[ni] = B_OFF + r * BK + ((g ^ sw4(r)) << 3);
  }

  f32x4 acc[4][8];
  #pragma unroll
  for (int mi = 0; mi < 4; ++mi)
    #pragma unroll
    for (int ni = 0; ni < 8; ++ni) {
      f32x4 z = {0.f, 0.f, 0.f, 0.f};
      acc[mi][ni] = z;
    }

  // ---- prologue: stage tiles 0 and 1 ----
  #pragma unroll
  for (int kt = 0; kt < 2; ++kt) {
    const int sb = kt * BUF_ELEMS;
    const int k0 = kt * BK;
    gload_lds16(srcA + k0, &lds[sb + dA]);
    #pragma unroll
    for (int i = 0; i < 4; ++i)
      gload_lds16(srcB + (size_t)(i * 128) * DIM + k0, &lds[sb + B_OFF + (i << 12) + dA]);
  }
  asm volatile("s_waitcnt vmcnt(5)" ::: "memory");   // tile 0 landed; tile 1 in flight
  __builtin_amdgcn_s_barrier();

  int b0 = 0;  // buffer of tile t (reading)
  int b2 = 2;  // buffer of tile t+2 (staging target) == buffer of dead tile t-1
  for (int t = 0; t < NK; ++t) {
    const int bb = b0 * BUF_ELEMS;
    const int sb = b2 * BUF_ELEMS;
    const int kst = ((t + 2) & (NK - 1)) * BK;       // wrap tail into dead buffers

    bf16x8 af[4], bf0[4], bf1[4];
    // ======== phase 0: A-frags + B-frags(lo), stage 3 issues, MFMA lo-half ========
    #pragma unroll
    for (int mi = 0; mi < 4; ++mi) af[mi] = *(const bf16x8*)&lds[bb + a_off[mi]];
    #pragma unroll
    for (int ni = 0; ni < 4; ++ni) bf0[ni] = *(const bf16x8*)&lds[bb + b_off[ni]];
    gload_lds16(srcA + kst, &lds[sb + dA]);
    gload_lds16(srcB + kst, &lds[sb + B_OFF + dA]);
    gload_lds16(srcB + (size_t)128 * DIM + kst, &lds[sb + B_OFF + 4096 + dA]);
    __builtin_amdgcn_s_barrier();
    asm volatile("s_waitcnt lgkmcnt(0)" ::: "memory");
    __builtin_amdgcn_sched_barrier(0);
    __builtin_amdgcn_s_setprio(1);
    #pragma unroll
    for (int mi = 0; mi < 4; ++mi)
      #pragma unroll
      for (int ni = 0; ni < 4; ++ni)
        acc[mi][ni] = __builtin_amdgcn_mfma_f32_16x16x32_bf16(af[mi], bf0[ni], acc[mi][ni], 0, 0, 0);
    __builtin_amdgcn_s_setprio(0);
    __builtin_amdgcn_s_barrier();

    // ======== phase 1: B-frags(hi), stage 2 issues, MFMA hi-half, counted vmcnt ========
    #pragma unroll
    for (int ni = 0; ni < 4; ++ni) bf1[ni] = *(const bf16x8*)&lds[bb + b_off[4 + ni]];
    gload_lds16(srcB + (size_t)256 * DIM + kst, &lds[sb + B_OFF + 8192 + dA]);
    gload_lds16(srcB + (size_t)384 * DIM + kst, &lds[sb + B_OFF + 12288 + dA]);
    __builtin_amdgcn_s_barrier();
    asm volatile("s_waitcnt lgkmcnt(0)" ::: "memory");
    __builtin_amdgcn_sched_barrier(0);
    __builtin_amdgcn_s_setprio(1);
    #pragma unroll
    for (int mi = 0; mi < 4; ++mi)
      #pragma unroll
      for (int ni = 0; ni < 4; ++ni)
        acc[mi][4 + ni] = __builtin_amdgcn_mfma_f32_16x16x32_bf16(af[mi], bf1[ni], acc[mi][4 + ni], 0, 0, 0);
    __builtin_amdgcn_s_setprio(0);
    asm volatile("s_waitcnt vmcnt(5)" ::: "memory");  // tile t+1 landed; t+2 stays in flight
    __builtin_amdgcn_s_barrier();

    b0 = (b0 == 2) ? 0 : b0 + 1;
    b2 = (b2 == 2) ? 0 : b2 + 1;
  }
  asm volatile("s_waitcnt vmcnt(0)" ::: "memory");   // drain trailing wrap-staging before exit

  // ======== epilogue: exp + masked reductions ========
  int cg[8], cl[8];
  #pragma unroll
  for (int ni = 0; ni < 8; ++ni) {
    cg[ni] = col0 + wn * 128 + ni * 16 + fr;
    cl[ni] = labels[cg[ni]];
  }
  #pragma unroll
  for (int mi = 0; mi < 4; ++mi) {
    #pragma unroll
    for (int j = 0; j < 4; ++j) {
      const int rgi = row0 + wm * 64 + mi * 16 + g * 4 + j;
      const int rlab = labels[rgi];
      float va = 0.f, vp = 0.f, vm = -__builtin_inff();
      #pragma unroll
      for (int ni = 0; ni < 8; ++ni) {
        float s10 = acc[mi][ni][j] * TEMP_INV;
        float e = __expf(s10);
        bool offd = (rgi != cg[ni]);
        float ea = offd ? e : 0.f;
        va += ea;
        vp += (rlab == cl[ni]) ? ea : 0.f;
        vm = offd ? fmaxf(vm, s10) : vm;
      }
      #pragma unroll
      for (int m = 1; m < 16; m <<= 1) {
        va += __shfl_xor(va, m);
        vp += __shfl_xor(vp, m);
        vm = fmaxf(vm, __shfl_xor(vm, m));
      }
      if (fr == 0) {
        int rl_ = wm * 64 + mi * 16 + g * 4 + j;
        red_sa[wn][rl_] = va;
        red_sp[wn][rl_] = vp;
        red_mx[wn][rl_] = vm;
      }
    }
  }
  __syncthreads();
  if (tid < BM) {
    size_t o = (size_t)blockIdx.y * N_ROWS + row0 + tid;
    ws_sa[o] = (red_sa[0][tid] + red_sa[1][tid]) + (red_sa[2][tid] + red_sa[3][tid]);
    ws_sp[o] = (red_sp[0][tid] + red_sp[1][tid]) + (red_sp[2][tid] + red_sp[3][tid]);
    ws_mx[o] = fmaxf(fmaxf(red_mx[0][tid], red_mx[1][tid]), fmaxf(red_mx[2][tid], red_mx[3][tid]));
  }
}

// -------- Kernel 3: combine chunk partials -> per-row loss --------
__global__ void finalize_rows_kernel(const float* __restrict__ ws_sp,
                                     const float* __restrict__ ws_sa,
                                     const float* __restrict__ ws_mx,
                                     float* __restrict__ ws_loss) {
  int r = blockIdx.x * blockDim.x + threadIdx.x;
  float sp = 0.f, sa = 0.f, mx = -__builtin_inff();
  #pragma unroll
  for (int c = 0; c < NCHUNK; ++c) {
    sp += ws_sp[(size_t)c * N_ROWS + r];
    sa += ws_sa[(size_t)c * N_ROWS + r];
    mx = fmaxf(mx, ws_mx[(size_t)c * N_ROWS + r]);
  }
  float frac = (sp + 1e-8f) / (sa + 1e-8f);
  frac = fminf(fmaxf(frac, 1e-8f), 1.0f);
  float loss = -logf(frac);
  if (sp == 0.0f) loss = -mx;   // no-positives fallback (every exp term > 0)
  ws_loss[r] = loss;
}

// -------- Kernel 4: deterministic mean --------
__global__ void mean_kernel(const float* __restrict__ ws_loss, float* __restrict__ out) {
  int t = threadIdx.x;
  float s = 0.f;
  for (int i = t; i < N_ROWS; i += 256) s += ws_loss[i];
  #pragma unroll
  for (int m = 1; m < 64; m <<= 1) s += __shfl_xor(s, m);
  __shared__ float wsum[4];
  if ((t & 63) == 0) wsum[t >> 6] = s;
  __syncthreads();
  if (t == 0) out[0] = (wsum[0] + wsum[1] + wsum[2] + wsum[3]) * (1.0f / N_ROWS);
}

extern "C" void kernel_launch(void* const* d_in, const int* in_sizes, int n_in,
                              void* d_out, int out_size, void* d_ws, size_t ws_size,
                              hipStream_t stream) {
  const float* ctx = (const float*)d_in[0];
  const float* gls = (const float*)d_in[1];
  const int* labels = (const int*)d_in[2];
  float* out = (float*)d_out;

  char* ws = (char*)d_ws;
  unsigned short* Cn = (unsigned short*)ws;                                  // 16 MiB
  unsigned short* Gn = (unsigned short*)(ws + (size_t)N_ROWS * DIM * 2);     // 16 MiB
  float* ws_sp = (float*)(ws + (size_t)2 * N_ROWS * DIM * 2);
  float* ws_sa = ws_sp + (size_t)NCHUNK * N_ROWS;
  float* ws_mx = ws_sa + (size_t)NCHUNK * N_ROWS;
  float* ws_loss = ws_mx + (size_t)NCHUNK * N_ROWS;

  hipLaunchKernelGGL(norm_bf16_kernel, dim3(2 * N_ROWS), dim3(256), 0, stream,
                     ctx, gls, Cn, Gn);
  hipLaunchKernelGGL(gemm_reduce_kernel, dim3(N_ROWS / BM, NCHUNK), dim3(512), 0, stream,
                     Cn, Gn, labels, ws_sp, ws_sa, ws_mx);
  hipLaunchKernelGGL(finalize_rows_kernel, dim3(N_ROWS / 256), dim3(256), 0, stream,
                     ws_sp, ws_sa, ws_mx, ws_loss);
  hipLaunchKernelGGL(mean_kernel, dim3(1), dim3(256), 0, stream, ws_loss, out);
}